// Round 4
// baseline (261.827 us; speedup 1.0000x reference)
//
#include <hip/hip_runtime.h>
#include <hip/hip_bf16.h>

// Problem constants (from reference setup_inputs)
#define BB 16        // batch
#define TT 288       // time steps
#define NN 4096      // nodes
#define RR 16        // regions
#define HH 10        // horizon
#define THALF (TT / 2)    // 144 — T split across the block's two thread-halves
#define GX (NN / 256)     // 16 node-groups of 256 nodes
#define NBLK (GX * BB)    // 256 blocks == blockDim, all co-resident (1024 waves)
#define NULLV (-1.0f)
#define MAGIC 0x5F17C0DEu // flag "done" value; 0xAA poison / garbage won't match

__device__ __forceinline__ void rel_store_u(unsigned int* p, unsigned int v) {
  __hip_atomic_store(p, v, __ATOMIC_RELEASE, __HIP_MEMORY_SCOPE_AGENT);
}
__device__ __forceinline__ unsigned int acq_load_u(const unsigned int* p) {
  return __hip_atomic_load(p, __ATOMIC_ACQUIRE, __HIP_MEMORY_SCOPE_AGENT);
}
__device__ __forceinline__ void rel_store_f(float* p, float v) {
  __hip_atomic_store(p, v, __ATOMIC_RELEASE, __HIP_MEMORY_SCOPE_AGENT);
}
__device__ __forceinline__ float acq_load_f(const float* p) {
  return __hip_atomic_load(p, __ATOMIC_ACQUIRE, __HIP_MEMORY_SCOPE_AGENT);
}

// ---------------------------------------------------------------------------
// Single fused kernel. grid (GX, BB) = (16,16) = 256 blocks x 256 threads.
// Block (gx,b): nodes [gx*256, gx*256+256) of batch b, full T.
//   threads 0..127  -> T in [0,144),  node pair n0 = gx*256 + 2*tl
//   threads 128..255-> T in [144,288), same node pairs (combined via LDS)
// Phase 1: float4-stream 151 MB, per-thread sum/count; block total ->
//          bsum/bcnt[blk] (plain store) + release flag1[blk].
// Grid sync: thread t acquire-spins on flag1[t] (256 flags == 256 threads).
// Phase 2: every block re-reduces the 256 block totals (1 KB, L2-hot) ->
//          gmean; impute; write tiled [B,H,N] (both halves write 5 horizons
//          each); LDS region hist -> release-stored rsB[blk][16] + flag2.
// Finalize: gx==0 blocks (one per batch) build the node histogram, spin on
//          their batch's 16 flag2, reduce rsB, write tiled [B,H,R].
// ---------------------------------------------------------------------------
__global__ __launch_bounds__(256) void k_fused(
    const float4* __restrict__ x4, const int* __restrict__ cluster,
    float* __restrict__ out, float* __restrict__ out2,
    float* __restrict__ bsum, float* __restrict__ bcntf,
    float* __restrict__ rsB,
    unsigned int* __restrict__ flag1, unsigned int* __restrict__ flag2) {
  const int tid  = threadIdx.x;
  const int gx   = blockIdx.x;          // node group 0..15
  const int b    = blockIdx.y;          // batch 0..15
  const int blk  = b * GX + gx;
  const int half = tid >> 7;            // which T-half this thread sums
  const int tl   = tid & 127;
  const int n0   = gx * 256 + tl * 2;

  __shared__ float shs[4], shc[4];
  __shared__ float4 comb[128];          // upper half's {s0,c0,s1,c1}
  __shared__ float2 predsh[128];        // preds shared back to upper half
  __shared__ float rsh[RR];
  __shared__ float sh_gmean;

  // ---- phase 1: stream this thread's T-half for its 2 nodes ----
  const float4* p = x4 + ((size_t)(b * TT + half * THALF) * NN + n0) / 2;
  float s0 = 0.f, s1 = 0.f, c0 = 0.f, c1 = 0.f;
#pragma unroll 8
  for (int t = 0; t < THALF; ++t) {
    float4 v = p[(size_t)t * (NN / 2)];
    s0 += (v.x != NULLV) ? v.x : 0.f;  c0 += (v.x != NULLV) ? 1.f : 0.f;
    s1 += (v.z != NULLV) ? v.z : 0.f;  c1 += (v.z != NULLV) ? 1.f : 0.f;
  }

  // block total (for the global imputation mean)
  float rs = s0 + s1, rc = c0 + c1;
  for (int off = 32; off; off >>= 1) {
    rs += __shfl_down(rs, off);
    rc += __shfl_down(rc, off);
  }
  if ((tid & 63) == 0) { shs[tid >> 6] = rs; shc[tid >> 6] = rc; }
  // publish upper-half per-node sums for the in-block combine
  if (half == 1) comb[tl] = make_float4(s0, c0, s1, c1);
  __syncthreads();
  if (tid == 0) {
    bsum[blk]  = shs[0] + shs[1] + shs[2] + shs[3];
    bcntf[blk] = shc[0] + shc[1] + shc[2] + shc[3];
    rel_store_u(&flag1[blk], MAGIC);    // release: bsum/bcnt visible first
  }

  // ---- grid-wide arrival: thread t waits for block t ----
  while (acq_load_u(&flag1[tid]) != MAGIC) __builtin_amdgcn_s_sleep(2);
  __syncthreads();                      // all 256 flags observed block-wide

  // ---- phase 2a: gmean from the 256 block totals (L2-hot, 1 KB) ----
  float gbs = bsum[tid], gbc = bcntf[tid];
  for (int off = 32; off; off >>= 1) {
    gbs += __shfl_down(gbs, off);
    gbc += __shfl_down(gbc, off);
  }
  if ((tid & 63) == 0) { shs[tid >> 6] = gbs; shc[tid >> 6] = gbc; }
  __syncthreads();
  if (tid == 0)
    sh_gmean = (shs[0] + shs[1] + shs[2] + shs[3]) /
               fmaxf(shc[0] + shc[1] + shc[2] + shc[3], 1.f);
  if (tid < RR) rsh[tid] = 0.f;
  __syncthreads();
  const float gmean = sh_gmean;

  // ---- phase 2b: combine halves, impute, regional LDS hist ----
  if (half == 0) {
    float4 up = comb[tl];
    s0 += up.x; c0 += up.y; s1 += up.z; c1 += up.w;
    const float inv_t = 1.0f / (float)TT;
    float pred0 = (s0 + ((float)TT - c0) * gmean) * inv_t;
    float pred1 = (s1 + ((float)TT - c1) * gmean) * inv_t;
    predsh[tl] = make_float2(pred0, pred1);
    atomicAdd(&rsh[cluster[n0]], pred0);
    atomicAdd(&rsh[cluster[n0 + 1]], pred1);
  }
  __syncthreads();

  // tiled [B,H,N] store: each half writes 5 horizons (float2/thread)
  {
    float2 pr = predsh[tl];
#pragma unroll
    for (int h = half * 5; h < half * 5 + 5; ++h)
      ((float2*)out)[((size_t)(b * HH + h) * NN + n0) / 2] = pr;
  }

  // per-block regional sums -> rsB (release) + arrival flag2
  if (tid < RR) rel_store_f(&rsB[blk * RR + tid], rsh[tid]);
  __syncthreads();
  if (tid == 0) rel_store_u(&flag2[blk], MAGIC);

  // ---- finalize: one block per batch writes the regional output ----
  if (gx == 0) {
    __shared__ unsigned int hist[RR];
    __shared__ float vsh[RR];
    if (tid < RR) hist[tid] = 0u;
    __syncthreads();
    for (int i = tid; i < NN; i += 256) atomicAdd(&hist[cluster[i]], 1u);
    if (tid < GX)
      while (acq_load_u(&flag2[b * GX + tid]) != MAGIC)
        __builtin_amdgcn_s_sleep(2);
    __syncthreads();
    if (tid < RR) {
      float s = 0.f;
#pragma unroll
      for (int g = 0; g < GX; ++g) s += acq_load_f(&rsB[(b * GX + g) * RR + tid]);
      vsh[tid] = s / fmaxf((float)hist[tid], 1.f);
    }
    __syncthreads();
    if (tid < HH * RR) {
      const int h = tid >> 4, r = tid & 15;
      out2[(size_t)(b * HH + h) * RR + r] = vsh[r];
    }
  }
}

extern "C" void kernel_launch(void* const* d_in, const int* in_sizes, int n_in,
                              void* d_out, int out_size, void* d_ws, size_t ws_size,
                              hipStream_t stream) {
  const float* x       = (const float*)d_in[0];  // [B,T,N,F=2] fp32
  const int*   cluster = (const int*)d_in[1];    // [N] int32
  float* out = (float*)d_out;                    // [B,H,N] then [B,H,R]

  // Workspace (20 KB): every slot plain-stored exactly once per call before
  // any read; flags use MAGIC so 0xAA poison / garbage never false-triggers.
  //   @0    bsum  float[256]
  //   @1K   bcntf float[256]
  //   @2K   rsB   float[256*16]
  //   @18K  flag1 uint[256]
  //   @19K  flag2 uint[256]
  float*        bsum  = (float*)d_ws;
  float*        bcntf = (float*)((char*)d_ws + 1024);
  float*        rsB   = (float*)((char*)d_ws + 2048);
  unsigned int* flag1 = (unsigned int*)((char*)d_ws + 18432);
  unsigned int* flag2 = (unsigned int*)((char*)d_ws + 19456);

  dim3 grid(GX, BB);   // 256 blocks x 256 threads — all co-resident
  k_fused<<<grid, 256, 0, stream>>>((const float4*)x, cluster,
                                    out, out + (size_t)BB * HH * NN,
                                    bsum, bcntf, rsB, flag1, flag2);
}

// Round 5
// 218.248 us; speedup vs baseline: 1.1997x; 1.1997x over previous
//
#include <hip/hip_runtime.h>
#include <hip/hip_bf16.h>

// Problem constants (from reference setup_inputs)
#define BB 16        // batch
#define TT 288       // time steps
#define NN 4096      // nodes
#define RR 16        // regions
#define HH 10        // horizon
#define TC 16        // time chunks -> 2048 blocks = 8 blocks/CU = 32 waves/CU
#define TSTEP (TT / TC)   // 18
#define LB 6              // load batch depth (6 float4 in flight per wave)
#define NBLK1 (8 * TC * BB)   // 2048
#define NULLV (-1.0f)

// ---------------------------------------------------------------------------
// Kernel 1: grid (NN/512, TC, BB) = (8,16,16) = 2048 blocks, 256 threads.
// Full-occupancy (32 waves/CU), 6-deep explicit load batching for MLP.
// Each thread owns 2 consecutive nodes via float4 loads (one float4 =
// {n0.f0, n0.f1, n1.f0, n1.f1}).  Writes packed {s0,c0,s1,c1} partials
// (counts <= 18, exact fp32) and per-block totals for the global mean.
// ---------------------------------------------------------------------------
__global__ __launch_bounds__(256) void k_partial(
    const float4* __restrict__ x4, float4* __restrict__ ps4,
    float* __restrict__ bsum, float* __restrict__ bcnt) {
  const int tid = threadIdx.x;
  const int n0  = blockIdx.x * 512 + tid * 2;
  const int tc  = blockIdx.y;
  const int b   = blockIdx.z;

  const float4* p = x4 + ((size_t)(b * TT + tc * TSTEP) * NN + n0) / 2;
  float s0 = 0.f, s1 = 0.f, c0 = 0.f, c1 = 0.f;
#pragma unroll
  for (int tb = 0; tb < TSTEP; tb += LB) {   // 3 batches of 6
    float4 v[LB];
#pragma unroll
    for (int j = 0; j < LB; ++j)
      v[j] = p[(size_t)(tb + j) * (NN / 2)];
#pragma unroll
    for (int j = 0; j < LB; ++j) {
      s0 += (v[j].x != NULLV) ? v[j].x : 0.f;
      c0 += (v[j].x != NULLV) ? 1.f : 0.f;
      s1 += (v[j].z != NULLV) ? v[j].z : 0.f;
      c1 += (v[j].z != NULLV) ? 1.f : 0.f;
    }
  }
  ps4[(((size_t)tc * BB + b) * NN + n0) / 2] = make_float4(s0, c0, s1, c1);

  // block total -> bsum/bcnt[blockLinear]  (plain float stores, no atomics)
  float rs = s0 + s1, rc = c0 + c1;
  for (int off = 32; off; off >>= 1) {
    rs += __shfl_down(rs, off);
    rc += __shfl_down(rc, off);
  }
  __shared__ float sh_s[4], sh_c[4];
  if ((tid & 63) == 0) { sh_s[tid >> 6] = rs; sh_c[tid >> 6] = rc; }
  __syncthreads();
  if (tid == 0) {
    const int blk = (blockIdx.z * TC + blockIdx.y) * 8 + blockIdx.x;
    bsum[blk] = sh_s[0] + sh_s[1] + sh_s[2] + sh_s[3];
    bcnt[blk] = sh_c[0] + sh_c[1] + sh_c[2] + sh_c[3];
  }
}

// ---------------------------------------------------------------------------
// Kernel 2: 64 blocks x 256 threads; each thread owns 4 consecutive nodes.
// (a) re-reduce the 2048 block totals (16 KB, L2-hot) -> gmean;
// (b) combine TC packed partials, impute, write tiled [B,H,N] (float4);
// (c) LDS region histogram -> per-block rsB (plain store, no global atomics).
// ---------------------------------------------------------------------------
__global__ __launch_bounds__(256) void k_pred(
    const float4* __restrict__ ps4,
    const float4* __restrict__ bsum4, const float4* __restrict__ bcnt4,
    const int4* __restrict__ cluster4,
    float4* __restrict__ out4, float* __restrict__ rsB) {
  const int tid = threadIdx.x;
  const int blk = blockIdx.x;          // 64 blocks
  const int b   = blk >> 2;
  const int n0  = (blk & 3) * 1024 + tid * 4;

  // ---- (a) gmean from 2048 block totals: 8 floats per thread ----
  float4 bs0 = bsum4[tid * 2], bs1 = bsum4[tid * 2 + 1];
  float4 bc0 = bcnt4[tid * 2], bc1 = bcnt4[tid * 2 + 1];
  float rs = bs0.x + bs0.y + bs0.z + bs0.w + bs1.x + bs1.y + bs1.z + bs1.w;
  float rc = bc0.x + bc0.y + bc0.z + bc0.w + bc1.x + bc1.y + bc1.z + bc1.w;
  for (int off = 32; off; off >>= 1) {
    rs += __shfl_down(rs, off);
    rc += __shfl_down(rc, off);
  }
  __shared__ float sh_s[4], sh_c[4], sh_gmean;
  if ((tid & 63) == 0) { sh_s[tid >> 6] = rs; sh_c[tid >> 6] = rc; }
  __syncthreads();
  if (tid == 0)
    sh_gmean = (sh_s[0] + sh_s[1] + sh_s[2] + sh_s[3]) /
               fmaxf(sh_c[0] + sh_c[1] + sh_c[2] + sh_c[3], 1.f);
  __syncthreads();
  const float gmean = sh_gmean;

  // ---- (b) combine packed partials {s0,c0,s1,c1}, impute, tile ----
  float4 s = make_float4(0.f, 0.f, 0.f, 0.f);
  float4 c = make_float4(0.f, 0.f, 0.f, 0.f);
#pragma unroll
  for (int tc = 0; tc < TC; ++tc) {
    const size_t o2 = (((size_t)tc * BB + b) * NN + n0) / 2;
    float4 p0 = ps4[o2];       // {s(n0), c(n0), s(n0+1), c(n0+1)}
    float4 p1 = ps4[o2 + 1];   // {s(n0+2), c(n0+2), s(n0+3), c(n0+3)}
    s.x += p0.x; c.x += p0.y; s.y += p0.z; c.y += p0.w;
    s.z += p1.x; c.z += p1.y; s.w += p1.z; c.w += p1.w;
  }
  const float inv_t = 1.0f / (float)TT;
  float4 pred;
  pred.x = (s.x + ((float)TT - c.x) * gmean) * inv_t;
  pred.y = (s.y + ((float)TT - c.y) * gmean) * inv_t;
  pred.z = (s.z + ((float)TT - c.z) * gmean) * inv_t;
  pred.w = (s.w + ((float)TT - c.w) * gmean) * inv_t;

#pragma unroll
  for (int h = 0; h < HH; ++h)
    out4[((size_t)(b * HH + h) * NN + n0) / 4] = pred;

  // ---- (c) per-block regional sums (plain store, no global atomics) ----
  __shared__ float rsh[RR];
  if (tid < RR) rsh[tid] = 0.0f;
  __syncthreads();
  int4 cl = cluster4[n0 / 4];
  atomicAdd(&rsh[cl.x], pred.x);
  atomicAdd(&rsh[cl.y], pred.y);
  atomicAdd(&rsh[cl.z], pred.z);
  atomicAdd(&rsh[cl.w], pred.w);
  __syncthreads();
  if (tid < RR) rsB[blk * RR + tid] = rsh[tid];
}

// ---------------------------------------------------------------------------
// Kernel 3: single block. Region histogram, combine 4 per-quarter block
// sums per (b,region), divide, write tiled [B,H,R].
// ---------------------------------------------------------------------------
__global__ __launch_bounds__(256) void k_final(
    const int* __restrict__ cluster, const float* __restrict__ rsB,
    float* __restrict__ out2) {
  __shared__ unsigned int hist[RR];
  const int tid = threadIdx.x;
  if (tid < RR) hist[tid] = 0u;
  __syncthreads();
  for (int i = tid; i < NN; i += 256) atomicAdd(&hist[cluster[i]], 1u);
  __syncthreads();
  const int b = tid >> 4;
  const int r = tid & 15;
  float s = 0.0f;
#pragma unroll
  for (int q = 0; q < 4; ++q) s += rsB[((b << 2) + q) * RR + r];
  const float v = s / fmaxf((float)hist[r], 1.0f);
#pragma unroll
  for (int h = 0; h < HH; ++h)
    out2[(size_t)(b * HH + h) * RR + r] = v;
}

extern "C" void kernel_launch(void* const* d_in, const int* in_sizes, int n_in,
                              void* d_out, int out_size, void* d_ws, size_t ws_size,
                              hipStream_t stream) {
  const float* x       = (const float*)d_in[0];  // [B,T,N,F=2] fp32
  const int*   cluster = (const int*)d_in[1];    // [N] int32
  float* out = (float*)d_out;                    // [B,H,N] then [B,H,R]

  // Workspace (every slot plain-stored before read each call; no zeroing):
  //   @0        ps    float4[TC*BB*NN/2]  (8 MB packed {s,c,s,c})
  //   @8M       bsum  float[2048]
  //   @8M+8K    bcnt  float[2048]
  //   @8M+16K   rsB   float[64*16]
  float* ps   = (float*)d_ws;
  float* bsum = (float*)((char*)d_ws + (size_t)TC * BB * NN * 8);
  float* bcnt = (float*)((char*)bsum + 8192);
  float* rsB  = (float*)((char*)bsum + 16384);

  dim3 g1(NN / 512, TC, BB);
  k_partial<<<g1, 256, 0, stream>>>((const float4*)x, (float4*)ps, bsum, bcnt);

  k_pred<<<64, 256, 0, stream>>>((const float4*)ps,
                                 (const float4*)bsum, (const float4*)bcnt,
                                 (const int4*)cluster, (float4*)out, rsB);

  k_final<<<1, 256, 0, stream>>>(cluster, rsB, out + (size_t)BB * HH * NN);
}